// Round 2
// baseline (310.203 us; speedup 1.0000x reference)
//
#include <hip/hip_runtime.h>

#define HH 479
#define WW 639
#define BATCH 8
#define NBLK (40 * 30 * 8)   // grid blocks = 9600

// depth layout: (B,1,H,W) -> b*H*W + r*W + c
// output pixel (i,j): window rows i-4..i+3, cols j-4..j+3 (zero-padded)
// a_c = (c - 319.5)/FX, b_r = (r - 239.5)/FY; point p = d*(a,b,1)
// Separable moments: per window-column c, row-reduce
//   S1=SUM d^2, Sb=SUM b d^2, Sbb=SUM b^2 d^2, T1=SUM d, Tb=SUM b d
// then per pixel: xx=SUM a^2 S1, xy=SUM a Sb, xz=SUM a S1, yy=SUM Sbb,
//                 yz=SUM Sb, zz=SUM S1, xs=SUM a T1, ys=SUM Tb, zs=SUM T1

__device__ __forceinline__ void solve_normal(
    float xx, float xy, float xz, float yy, float yz, float zz,
    float xs, float ys, float zs,
    float a_c, float b_c, float d0,
    float* nx, float* ny, float* nz)
{
    // ATA + eps*I, solved in double (f32 Cramer has ~1e8 cancellation at corners)
    const double EPSV = 1e-6;
    double p = (double)xx + EPSV, q = (double)xy, r = (double)xz;
    double s = (double)yy + EPSV, t = (double)yz, u = (double)zz + EPSV;
    double c00 = s * u - t * t;
    double c01 = r * t - q * u;
    double c02 = q * t - r * s;
    double det = p * c00 + q * c01 + r * c02;
    double c11 = p * u - r * r;
    double c12 = q * r - p * t;
    double c22 = p * s - q * q;
    double m0 = c00 * (double)xs + c01 * (double)ys + c02 * (double)zs;
    double m1 = c01 * (double)xs + c11 * (double)ys + c12 * (double)zs;
    double m2 = c02 * (double)xs + c12 * (double)ys + c22 * (double)zs;
    double nrm = sqrt(m0 * m0 + m1 * m1 + m2 * m2);
    double inv = 1.0 / nrm;
    if (det < 0.0) inv = -inv;
    double ux = m0 * inv, uy = m1 * inv, uz = m2 * inv;
    double dot = (double)d0 * (ux * (double)a_c + uy * (double)b_c + uz);
    if (dot > 0.0) { ux = -ux; uy = -uy; uz = -uz; }
    if (!(d0 > 0.0f)) { ux = 0.0; uy = 0.0; uz = 0.0; }
    *nx = (float)ux; *ny = (float)uy; *nz = (float)uz;
}

__global__ __launch_bounds__(256)
void ppal_main(const float* __restrict__ pred, const float* __restrict__ gt,
               double* __restrict__ acc, unsigned int* __restrict__ cnt,
               float* __restrict__ out)
{
    const int tx = threadIdx.x;        // 0..15
    const int ty = threadIdx.y;        // 0..15
    const int tid = ty * 16 + tx;
    const int j0 = blockIdx.x * 16;
    const int i0 = blockIdx.y * 16;
    const int b  = blockIdx.z;

    const float invFX = 1.0f / 518.857f;
    const float invFY = 1.0f / 519.469f;

    // depth tile: rows i0-4..i0+18 (23), cols j0-4..j0+18 (23); stride 24
    __shared__ float sd[2][23 * 24];
    // column sums: [input][value][i*24+c], i in 0..15, c in 0..23 (c=23 pad/unused)
    __shared__ float cs[2][5][16 * 24];

    const float* src0 = pred + (size_t)b * (HH * WW);
    const float* src1 = gt   + (size_t)b * (HH * WW);
    for (int idx = tid; idx < 23 * 23; idx += 256) {
        int lr = idx / 23, lc = idx - lr * 23;
        int r = i0 - 4 + lr, c = j0 - 4 + lc;
        bool ok = (r >= 0) && (r < HH) && (c >= 0) && (c < WW);
        int off = r * WW + c;
        sd[0][lr * 24 + lc] = ok ? src0[off] : 0.0f;
        sd[1][lr * 24 + lc] = ok ? src1[off] : 0.0f;
    }
    __syncthreads();

    // ---- stage 1: per-(output-row i, window-col c) row reductions ----
    // tasks t in [0,384): i = t/24 (magic), c = t%24 -> consecutive LDS addrs per wave
    for (int t = tid; t < 384; t += 256) {
        int i = (int)(((unsigned)t * 43691u) >> 20);   // t/24, exact for t<384
        int c = t - i * 24;
        float b0 = ((float)(i0 + i - 4) - 239.5f) * invFY;
        float S1[2] = {0.f, 0.f}, Sb[2] = {0.f, 0.f}, Sbb[2] = {0.f, 0.f};
        float T1[2] = {0.f, 0.f}, Tb[2] = {0.f, 0.f};
#pragma unroll
        for (int dr = 0; dr < 8; ++dr) {
            float bv = b0 + (float)dr * invFY;
#pragma unroll
            for (int k = 0; k < 2; ++k) {
                float d  = sd[k][(i + dr) * 24 + c];
                float bd = bv * d;
                T1[k] += d;
                Tb[k] += bd;
                S1[k]  = fmaf(d,  d,  S1[k]);
                Sb[k]  = fmaf(bd, d,  Sb[k]);
                Sbb[k] = fmaf(bd, bd, Sbb[k]);
            }
        }
        int base = i * 24 + c;
#pragma unroll
        for (int k = 0; k < 2; ++k) {
            cs[k][0][base] = S1[k];
            cs[k][1][base] = Sb[k];
            cs[k][2][base] = Sbb[k];
            cs[k][3][base] = T1[k];
            cs[k][4][base] = Tb[k];
        }
    }
    __syncthreads();

    // ---- stage 2: per-pixel column combine + solve ----
    const int i = i0 + ty, j = j0 + tx;
    const bool valid = (i < HH) && (j < WW);

    float contrib = 0.0f;
    if (valid) {
        float aa[8], a2[8];
#pragma unroll
        for (int dc = 0; dc < 8; ++dc) {
            float a = ((float)(j - 4 + dc) - 319.5f) * invFX;
            aa[dc] = a;
            a2[dc] = a * a;
        }
        float bc = ((float)i - 239.5f) * invFY;

        float n2[2][3];
#pragma unroll 1
        for (int k = 0; k < 2; ++k) {
            float xx = 0.f, xy = 0.f, xz = 0.f, yy = 0.f, yz = 0.f, zz = 0.f;
            float xs = 0.f, ys = 0.f, zs = 0.f;
            const int rbase = ty * 24 + tx;
#pragma unroll
            for (int dc = 0; dc < 8; ++dc) {
                int o = rbase + dc;
                float S1  = cs[k][0][o];
                float Sb  = cs[k][1][o];
                float Sbb = cs[k][2][o];
                float T1  = cs[k][3][o];
                float Tb  = cs[k][4][o];
                zz += S1;  yz += Sb;  yy += Sbb;
                zs += T1;  ys += Tb;
                xz = fmaf(aa[dc], S1, xz);
                xy = fmaf(aa[dc], Sb, xy);
                xs = fmaf(aa[dc], T1, xs);
                xx = fmaf(a2[dc], S1, xx);
            }
            float d0 = sd[k][(ty + 4) * 24 + (tx + 4)];
            solve_normal(xx, xy, xz, yy, yz, zz, xs, ys, zs,
                         aa[4], bc, d0, &n2[k][0], &n2[k][1], &n2[k][2]);
        }
        contrib = fabsf(n2[0][0] - n2[1][0])
                + fabsf(n2[0][1] - n2[1][1])
                + fabsf(n2[0][2] - n2[1][2]);
    }

    // ---- reduction: wave shuffle -> LDS -> one atomic/block; last block finalizes ----
    float v = contrib;
#pragma unroll
    for (int off = 32; off > 0; off >>= 1) v += __shfl_down(v, off, 64);
    __shared__ float wsum[4];
    int wid = tid >> 6, lane = tid & 63;
    if (lane == 0) wsum[wid] = v;
    __syncthreads();
    if (tid == 0) {
        double bs = (double)wsum[0] + (double)wsum[1] + (double)wsum[2] + (double)wsum[3];
        atomicAdd(acc, bs);
        __threadfence();
        unsigned int old = atomicAdd(cnt, 1u);
        if (old == NBLK - 1) {
            double total = atomicAdd(acc, 0.0);   // coherent device-scope read
            out[0] = (float)(total * (1.0 / 7345944.0));  // mean over B*3*H*W
        }
    }
}

extern "C" void kernel_launch(void* const* d_in, const int* in_sizes, int n_in,
                              void* d_out, int out_size, void* d_ws, size_t ws_size,
                              hipStream_t stream)
{
    const float* pred = (const float*)d_in[0];
    const float* gt   = (const float*)d_in[1];
    float* out = (float*)d_out;
    double* acc = (double*)d_ws;
    unsigned int* cnt = (unsigned int*)((char*)d_ws + 8);

    hipMemsetAsync(d_ws, 0, 16, stream);

    dim3 grid((WW + 15) / 16, (HH + 15) / 16, BATCH);  // 40 x 30 x 8 = 9600
    dim3 block(16, 16);
    ppal_main<<<grid, block, 0, stream>>>(pred, gt, acc, cnt, out);
}